// Round 9
// baseline (2216.129 us; speedup 1.0000x reference)
//
#include <hip/hip_runtime.h>
#include <math.h>

#define NEG_SLOPE 0.2f

// native f32 atomic (global_atomic_add_f32) — no CAS loop. d_ws/d_out are
// ordinary coarse-grained device allocations, where this is architecturally
// supported. (R8 profile: CAS atomicAdd produced 1.7 GB of write traffic and
// 1420 us on layer-1 agg; VALUBusy 3%, HBM 18% -> pure RMW serialization.)
static __device__ __forceinline__ void atomAdd(float* a, float v) {
    unsafeAtomicAdd(a, v);
}

// Edge-layout probe (wave-uniform): int64 indices (< 2^31) have all-zero odd
// 32-bit words; int32 real edge data has ~U[0,N) odd words. FP prob ~1e-19.
static __device__ __forceinline__ bool edges_are_i64(const int* __restrict__ ei) {
    return (ei[1] | ei[3] | ei[5] | ei[7]) == 0;
}

static __device__ __forceinline__ void ldedge(const int* __restrict__ ei, int e, int E,
                                              bool i64, int& s, int& d) {
    if (i64) { s = ei[2 * e]; d = ei[2 * (E + e)]; }
    else     { s = ei[e];     d = ei[E + e]; }
}

__global__ void fill_f32(float* __restrict__ p, float v, int n) {
    int i = blockIdx.x * blockDim.x + threadIdx.x;
    if (i < n) p[i] = v;
}

// h1[N,128] = x[N,64] @ W1[64,128], fp32. 2 rows / 256-thread block.
__global__ __launch_bounds__(256) void gemm1_k(const float* __restrict__ x,
                                               const float* __restrict__ W,
                                               float* __restrict__ h, int N) {
    __shared__ float Ws[64 * 128];
    __shared__ float xs[2 * 64];
    int tid = threadIdx.x;
    for (int i = tid; i < 64 * 128; i += 256) Ws[i] = W[i];
    int row0 = blockIdx.x * 2;
    for (int i = tid; i < 2 * 64; i += 256) {
        int r = row0 + i / 64;
        xs[i] = (r < N) ? x[(size_t)r * 64 + (i % 64)] : 0.0f;
    }
    __syncthreads();
    int r = row0 + tid / 128;
    if (r >= N) return;
    int j = tid % 128;
    const float* xr = &xs[(tid / 128) * 64];
    float acc = 0.0f;
#pragma unroll
    for (int k = 0; k < 64; ++k) acc += xr[k] * Ws[k * 128 + j];
    h[(size_t)r * 128 + j] = acc;
}

// h2[N,32] = hact[N,128] @ W2[128,32]. 8 rows / block.
__global__ __launch_bounds__(256) void gemm2_k(const float* __restrict__ hact,
                                               const float* __restrict__ W,
                                               float* __restrict__ h2, int N) {
    __shared__ float Ws[128 * 32];
    __shared__ float xs[8 * 128];
    int tid = threadIdx.x;
    for (int i = tid; i < 128 * 32; i += 256) Ws[i] = W[i];
    int row0 = blockIdx.x * 8;
    for (int i = tid; i < 8 * 128; i += 256) {
        int r = row0 + i / 128;
        xs[i] = (r < N) ? hact[(size_t)r * 128 + (i % 128)] : 0.0f;
    }
    __syncthreads();
    int r = row0 + tid / 32;
    if (r >= N) return;
    int j = tid % 32;
    const float* xr = &xs[(tid / 32) * 128];
    float acc = 0.0f;
#pragma unroll 16
    for (int k = 0; k < 128; ++k) acc += xr[k] * Ws[k * 32 + j];
    h2[(size_t)r * 32 + j] = acc;
}

// a_src[n,h] = <h[n,h,:], att_src[h,:]> ; same for dst. One thread per (n,h).
template <int H>
__global__ void att_k(const float* __restrict__ h,
                      const float* __restrict__ aw_s,
                      const float* __restrict__ aw_d,
                      float* __restrict__ as_, float* __restrict__ ad_, int N) {
    int i = blockIdx.x * blockDim.x + threadIdx.x;
    if (i >= N * H) return;
    int hd = i % H;
    const float* hr = h + (size_t)(i / H) * (H * 32) + hd * 32;
    float s = 0.0f, d = 0.0f;
#pragma unroll
    for (int c = 0; c < 32; ++c) {
        float v = hr[c];
        s += v * aw_s[hd * 32 + c];
        d += v * aw_d[hd * 32 + c];
    }
    as_[i] = s;
    ad_[i] = d;
}

// den[d,h] += exp(leaky(a_src[s,h]+a_dst[d,h]))   (no max-shift: |e| is O(5))
template <int H>
__global__ void edge_den_k(const int* __restrict__ ei, const float* __restrict__ asrc,
                           const float* __restrict__ adst, float* __restrict__ den,
                           int E, int N) {
    int e = blockIdx.x * blockDim.x + threadIdx.x;
    if (e >= E + N) return;
    bool i64 = edges_are_i64(ei);
    int s, d;
    if (e < E) ldedge(ei, e, E, i64, s, d);
    else       { s = d = e - E; }
#pragma unroll
    for (int h = 0; h < H; ++h) {
        float v = asrc[s * H + h] + adst[d * H + h];
        v = v > 0.0f ? v : NEG_SLOPE * v;
        atomAdd(&den[d * H + h], __expf(v));
    }
}

// out[dst] += (exp(e)/den[dst]) * h[src]; (H*C)/4 lanes per edge, float4 gathers.
template <int H, int C>
__global__ __launch_bounds__(256) void edge_agg_k(const int* __restrict__ ei,
                                                  const float* __restrict__ asrc,
                                                  const float* __restrict__ adst,
                                                  const float* __restrict__ den,
                                                  const float* __restrict__ h,
                                                  float* __restrict__ out, int E, int N) {
    constexpr int CT = H * C;
    constexpr int L = CT / 4;
    int gt = blockIdx.x * 256 + threadIdx.x;
    int e = gt / L;
    int lane = gt % L;
    if (e >= E + N) return;
    bool i64 = edges_are_i64(ei);
    int s, d;
    if (e < E) ldedge(ei, e, E, i64, s, d);
    else       { s = d = e - E; }
    int hd = (lane * 4) / C;
    float v = asrc[s * H + hd] + adst[d * H + hd];
    v = v > 0.0f ? v : NEG_SLOPE * v;
    float alpha = __expf(v) / den[d * H + hd];
    const float4 hv = *(const float4*)(h + (size_t)s * CT + lane * 4);
    float* o = out + (size_t)d * CT + lane * 4;
    atomAdd(o + 0, hv.x * alpha);
    atomAdd(o + 1, hv.y * alpha);
    atomAdd(o + 2, hv.z * alpha);
    atomAdd(o + 3, hv.w * alpha);
}

__global__ void elu_bias_k(const float* __restrict__ a, const float* __restrict__ b,
                           float* __restrict__ o, int n) {
    int i = blockIdx.x * blockDim.x + threadIdx.x;
    if (i >= n) return;
    float v = a[i] + b[i & 127];
    o[i] = v > 0.0f ? v : expm1f(v);
}

// column sums of out2[N,32] -> atomicAdd into gsum[32]
__global__ __launch_bounds__(256) void colmean_k(const float* __restrict__ out2,
                                                 float* __restrict__ gsum, int N) {
    __shared__ float lds[256];
    int tid = threadIdx.x;
    int c = tid % 32;
    int rg = tid / 32;
    float acc = 0.0f;
    for (int r = blockIdx.x * 8 + rg; r < N; r += gridDim.x * 8)
        acc += out2[(size_t)r * 32 + c];
    lds[tid] = acc;
    __syncthreads();
    if (tid < 32) {
        float s = 0.0f;
#pragma unroll
        for (int g = 0; g < 8; ++g) s += lds[g * 32 + tid];
        atomAdd(&gsum[tid], s);
    }
}

// output is FLOAT32 (reference returns fp32 softmax)
__global__ void final_k(const float* __restrict__ gsum, const float* __restrict__ b2w,
                        const float* __restrict__ linW, const float* __restrict__ linb,
                        float* __restrict__ out, int N) {
    if (threadIdx.x != 0 || blockIdx.x != 0) return;
    float g[32];
#pragma unroll
    for (int c = 0; c < 32; ++c) g[c] = gsum[c] / (float)N + b2w[c];
    float lo[3];
#pragma unroll
    for (int j = 0; j < 3; ++j) {
        float acc = linb[j];
#pragma unroll
        for (int c = 0; c < 32; ++c) acc += g[c] * linW[c * 3 + j];
        lo[j] = acc;
    }
    float mx = fmaxf(lo[0], fmaxf(lo[1], lo[2]));
    float ex[3], se = 0.0f;
#pragma unroll
    for (int j = 0; j < 3; ++j) { ex[j] = __expf(lo[j] - mx); se += ex[j]; }
#pragma unroll
    for (int j = 0; j < 3; ++j) out[j] = ex[j] / se;
}

extern "C" void kernel_launch(void* const* d_in, const int* in_sizes, int n_in,
                              void* d_out, int out_size, void* d_ws, size_t ws_size,
                              hipStream_t stream) {
    const float* x    = (const float*)d_in[0];
    const float* W1   = (const float*)d_in[1];
    const float* as1w = (const float*)d_in[2];
    const float* ad1w = (const float*)d_in[3];
    const float* b1   = (const float*)d_in[4];
    const float* W2   = (const float*)d_in[5];
    const float* as2w = (const float*)d_in[6];
    const float* ad2w = (const float*)d_in[7];
    const float* b2w  = (const float*)d_in[8];
    const float* linW = (const float*)d_in[9];
    const float* linb = (const float*)d_in[10];
    const int*   ei   = (const int*)d_in[11];

    const int N  = in_sizes[0] / 64;       // 50000
    const int E  = in_sizes[11] / 2;       // 800000
    const int ET = E + N;

    float* ws = (float*)d_ws;
    float* h1    = ws;                       // N*128, reused as hact after ELU
    float* out1  = h1 + (size_t)N * 128;     // N*128
    float* asrc1 = out1 + (size_t)N * 128;   // N*4
    float* adst1 = asrc1 + (size_t)N * 4;    // N*4
    float* den1  = adst1 + (size_t)N * 4;    // N*4
    // layer-2 buffers alias out1 (dead after elu_bias_k); fills issued after elu.
    float* h2    = out1;                     // N*32
    float* out2  = h2 + (size_t)N * 32;      // N*32
    float* asrc2 = out2 + (size_t)N * 32;    // N
    float* adst2 = asrc2 + (size_t)N;        // N
    float* den2  = adst2 + (size_t)N;        // N
    float* gsum  = den2 + (size_t)N;         // 32

    auto cdiv = [](int a, int b) { return (a + b - 1) / b; };

    // ---- layer 1 ----
    fill_f32<<<cdiv(N * 128, 256), 256, 0, stream>>>(out1, 0.0f, N * 128);
    fill_f32<<<cdiv(N * 4, 256), 256, 0, stream>>>(den1, 0.0f, N * 4);
    gemm1_k<<<cdiv(N, 2), 256, 0, stream>>>(x, W1, h1, N);
    att_k<4><<<cdiv(N * 4, 256), 256, 0, stream>>>(h1, as1w, ad1w, asrc1, adst1, N);
    edge_den_k<4><<<cdiv(ET, 256), 256, 0, stream>>>(ei, asrc1, adst1, den1, E, N);
    edge_agg_k<4, 32><<<cdiv(ET * 32, 256), 256, 0, stream>>>(ei, asrc1, adst1, den1, h1, out1, E, N);
    elu_bias_k<<<cdiv(N * 128, 256), 256, 0, stream>>>(out1, b1, h1, N * 128);  // hact -> h1

    // ---- layer 2 (fills after elu: out1 region is now dead) ----
    fill_f32<<<cdiv(N * 32, 256), 256, 0, stream>>>(out2, 0.0f, N * 32);
    fill_f32<<<cdiv(N, 256), 256, 0, stream>>>(den2, 0.0f, N);
    fill_f32<<<1, 32, 0, stream>>>(gsum, 0.0f, 32);
    gemm2_k<<<cdiv(N, 8), 256, 0, stream>>>(h1, W2, h2, N);
    att_k<1><<<cdiv(N, 256), 256, 0, stream>>>(h2, as2w, ad2w, asrc2, adst2, N);
    edge_den_k<1><<<cdiv(ET, 256), 256, 0, stream>>>(ei, asrc2, adst2, den2, E, N);
    edge_agg_k<1, 32><<<cdiv(ET * 8, 256), 256, 0, stream>>>(ei, asrc2, adst2, den2, h2, out2, E, N);

    // ---- readout ----
    colmean_k<<<256, 256, 0, stream>>>(out2, gsum, N);
    final_k<<<1, 64, 0, stream>>>(gsum, b2w, linW, linb, (float*)d_out, N);
}

// Round 10
// 450.908 us; speedup vs baseline: 4.9148x; 4.9148x over previous
//
#include <hip/hip_runtime.h>
#include <math.h>

#define NEG_SLOPE 0.2f

// native f32 atomic — only used for the tiny gsum reduction now
static __device__ __forceinline__ void atomAdd(float* a, float v) {
    unsafeAtomicAdd(a, v);
}

// Edge-layout probe (wave-uniform): int64 indices (< 2^31) have all-zero odd
// 32-bit words; int32 real edge data has ~U[0,N) odd words.
static __device__ __forceinline__ bool edges_are_i64(const int* __restrict__ ei) {
    return (ei[1] | ei[3] | ei[5] | ei[7]) == 0;
}
static __device__ __forceinline__ int ldsrc(const int* __restrict__ ei, int e, int E, bool i64) {
    return i64 ? ei[2 * e] : ei[e];
}
static __device__ __forceinline__ int lddst(const int* __restrict__ ei, int e, int E, bool i64) {
    return i64 ? ei[2 * (E + e)] : ei[E + e];
}

__global__ void zero_i32(int* __restrict__ p, int n) {
    int i = blockIdx.x * blockDim.x + threadIdx.x;
    if (i < n) p[i] = 0;
}
__global__ void fill_f32(float* __restrict__ p, float v, int n) {
    int i = blockIdx.x * blockDim.x + threadIdx.x;
    if (i < n) p[i] = v;
}

// ---- CSR build (dst-sorted, self-loops included), shared by both layers ----
__global__ void hist_k(const int* __restrict__ ei, int* __restrict__ deg, int E, int N) {
    int e = blockIdx.x * blockDim.x + threadIdx.x;
    if (e >= E + N) return;
    bool i64 = edges_are_i64(ei);
    int d = (e < E) ? lddst(ei, e, E, i64) : (e - E);
    atomicAdd(&deg[d], 1);
}

// exclusive scan of deg -> excl (per 256-chunk), chunk totals -> bsum
__global__ __launch_bounds__(256) void scan1_k(const int* __restrict__ deg,
                                               int* __restrict__ excl,
                                               int* __restrict__ bsum, int N) {
    __shared__ int sd[256];
    int t = threadIdx.x, i = blockIdx.x * 256 + t;
    int v = (i < N) ? deg[i] : 0;
    sd[t] = v; __syncthreads();
    for (int off = 1; off < 256; off <<= 1) {
        int x = (t >= off) ? sd[t - off] : 0;
        __syncthreads();
        sd[t] += x;
        __syncthreads();
    }
    if (i < N) excl[i] = sd[t] - v;
    if (t == 255) bsum[blockIdx.x] = sd[255];
}
// exclusive scan of bsum in place (nb <= 256)
__global__ __launch_bounds__(256) void scan2_k(int* __restrict__ bsum, int nb) {
    __shared__ int sd[256];
    int t = threadIdx.x;
    int v = (t < nb) ? bsum[t] : 0;
    sd[t] = v; __syncthreads();
    for (int off = 1; off < 256; off <<= 1) {
        int x = (t >= off) ? sd[t - off] : 0;
        __syncthreads();
        sd[t] += x;
        __syncthreads();
    }
    if (t < nb) bsum[t] = sd[t] - v;
}
__global__ void scan3_k(const int* __restrict__ excl, const int* __restrict__ bsum,
                        int* __restrict__ row_ptr, int* __restrict__ cursor, int N, int ET) {
    int i = blockIdx.x * blockDim.x + threadIdx.x;
    if (i < N) { int r = excl[i] + bsum[i >> 8]; row_ptr[i] = r; cursor[i] = r; }
    if (i == N) row_ptr[N] = ET;
}
__global__ void scatter_k(const int* __restrict__ ei, int* __restrict__ cursor,
                          int* __restrict__ col, int E, int N) {
    int e = blockIdx.x * blockDim.x + threadIdx.x;
    if (e >= E + N) return;
    bool i64 = edges_are_i64(ei);
    int s, d;
    if (e < E) { s = ldsrc(ei, e, E, i64); d = lddst(ei, e, E, i64); }
    else       { s = d = e - E; }
    int pos = atomicAdd(&cursor[d], 1);
    col[pos] = s;
}

// ---- dense kernels (unchanged from R9) ----
__global__ __launch_bounds__(256) void gemm1_k(const float* __restrict__ x,
                                               const float* __restrict__ W,
                                               float* __restrict__ h, int N) {
    __shared__ float Ws[64 * 128];
    __shared__ float xs[2 * 64];
    int tid = threadIdx.x;
    for (int i = tid; i < 64 * 128; i += 256) Ws[i] = W[i];
    int row0 = blockIdx.x * 2;
    for (int i = tid; i < 2 * 64; i += 256) {
        int r = row0 + i / 64;
        xs[i] = (r < N) ? x[(size_t)r * 64 + (i % 64)] : 0.0f;
    }
    __syncthreads();
    int r = row0 + tid / 128;
    if (r >= N) return;
    int j = tid % 128;
    const float* xr = &xs[(tid / 128) * 64];
    float acc = 0.0f;
#pragma unroll
    for (int k = 0; k < 64; ++k) acc += xr[k] * Ws[k * 128 + j];
    h[(size_t)r * 128 + j] = acc;
}

__global__ __launch_bounds__(256) void gemm2_k(const float* __restrict__ hact,
                                               const float* __restrict__ W,
                                               float* __restrict__ h2, int N) {
    __shared__ float Ws[128 * 32];
    __shared__ float xs[8 * 128];
    int tid = threadIdx.x;
    for (int i = tid; i < 128 * 32; i += 256) Ws[i] = W[i];
    int row0 = blockIdx.x * 8;
    for (int i = tid; i < 8 * 128; i += 256) {
        int r = row0 + i / 128;
        xs[i] = (r < N) ? hact[(size_t)r * 128 + (i % 128)] : 0.0f;
    }
    __syncthreads();
    int r = row0 + tid / 32;
    if (r >= N) return;
    int j = tid % 32;
    const float* xr = &xs[(tid / 32) * 128];
    float acc = 0.0f;
#pragma unroll 16
    for (int k = 0; k < 128; ++k) acc += xr[k] * Ws[k * 32 + j];
    h2[(size_t)r * 32 + j] = acc;
}

template <int H>
__global__ void att_k(const float* __restrict__ h,
                      const float* __restrict__ aw_s,
                      const float* __restrict__ aw_d,
                      float* __restrict__ as_, float* __restrict__ ad_, int N) {
    int i = blockIdx.x * blockDim.x + threadIdx.x;
    if (i >= N * H) return;
    int hd = i % H;
    const float* hr = h + (size_t)(i / H) * (H * 32) + hd * 32;
    float s = 0.0f, d = 0.0f;
#pragma unroll
    for (int c = 0; c < 32; ++c) {
        float v = hr[c];
        s += v * aw_s[hd * 32 + c];
        d += v * aw_d[hd * 32 + c];
    }
    as_[i] = s;
    ad_[i] = d;
}

// ---- pull-mode aggregation: zero atomics, fused softmax-denominator ----
// Layer 1 (H=4, C=32): one 64-lane wave per dst; lane owns channels 2l,2l+1
// (head = l/16). Denominator accumulated redundantly per lane (wave-uniform
// per head) — no cross-lane reduction needed.
__global__ __launch_bounds__(256) void pull_agg1_k(const int* __restrict__ row_ptr,
                                                   const int* __restrict__ col,
                                                   const float* __restrict__ asrc,
                                                   const float* __restrict__ adst,
                                                   const float* __restrict__ h,
                                                   float* __restrict__ out, int N) {
    int wave = (blockIdx.x * 256 + threadIdx.x) >> 6;
    int lane = threadIdx.x & 63;
    if (wave >= N) return;
    const int d = wave;
    const int hd = lane >> 4;
    const float ad = adst[d * 4 + hd];
    const int beg = row_ptr[d], end = row_ptr[d + 1];
    float acc0 = 0.0f, acc1 = 0.0f, den = 0.0f;
    for (int i = beg; i < end; ++i) {
        int s = col[i];
        float v = asrc[s * 4 + hd] + ad;
        v = v > 0.0f ? v : NEG_SLOPE * v;
        float p = __expf(v);
        den += p;
        const float2 hv = *(const float2*)(h + (size_t)s * 128 + lane * 2);
        acc0 += p * hv.x;
        acc1 += p * hv.y;
    }
    float inv = 1.0f / den;                    // den>0: self-loop guaranteed
    *(float2*)(out + (size_t)d * 128 + lane * 2) = make_float2(acc0 * inv, acc1 * inv);
}

// Layer 2 (H=1, C=32): one 32-lane group per dst; lane owns one channel.
__global__ __launch_bounds__(256) void pull_agg2_k(const int* __restrict__ row_ptr,
                                                   const int* __restrict__ col,
                                                   const float* __restrict__ asrc,
                                                   const float* __restrict__ adst,
                                                   const float* __restrict__ h,
                                                   float* __restrict__ out, int N) {
    int grp = (blockIdx.x * 256 + threadIdx.x) >> 5;
    int lane = threadIdx.x & 31;
    if (grp >= N) return;
    const int d = grp;
    const float ad = adst[d];
    const int beg = row_ptr[d], end = row_ptr[d + 1];
    float acc = 0.0f, den = 0.0f;
    for (int i = beg; i < end; ++i) {
        int s = col[i];
        float v = asrc[s] + ad;
        v = v > 0.0f ? v : NEG_SLOPE * v;
        float p = __expf(v);
        den += p;
        acc += p * h[(size_t)s * 32 + lane];
    }
    out[(size_t)d * 32 + lane] = acc / den;
}

__global__ void elu_bias_k(const float* __restrict__ a, const float* __restrict__ b,
                           float* __restrict__ o, int n) {
    int i = blockIdx.x * blockDim.x + threadIdx.x;
    if (i >= n) return;
    float v = a[i] + b[i & 127];
    o[i] = v > 0.0f ? v : expm1f(v);
}

__global__ __launch_bounds__(256) void colmean_k(const float* __restrict__ out2,
                                                 float* __restrict__ gsum, int N) {
    __shared__ float lds[256];
    int tid = threadIdx.x;
    int c = tid % 32;
    int rg = tid / 32;
    float acc = 0.0f;
    for (int r = blockIdx.x * 8 + rg; r < N; r += gridDim.x * 8)
        acc += out2[(size_t)r * 32 + c];
    lds[tid] = acc;
    __syncthreads();
    if (tid < 32) {
        float s = 0.0f;
#pragma unroll
        for (int g = 0; g < 8; ++g) s += lds[g * 32 + tid];
        atomAdd(&gsum[tid], s);
    }
}

__global__ void final_k(const float* __restrict__ gsum, const float* __restrict__ b2w,
                        const float* __restrict__ linW, const float* __restrict__ linb,
                        float* __restrict__ out, int N) {
    if (threadIdx.x != 0 || blockIdx.x != 0) return;
    float g[32];
#pragma unroll
    for (int c = 0; c < 32; ++c) g[c] = gsum[c] / (float)N + b2w[c];
    float lo[3];
#pragma unroll
    for (int j = 0; j < 3; ++j) {
        float acc = linb[j];
#pragma unroll
        for (int c = 0; c < 32; ++c) acc += g[c] * linW[c * 3 + j];
        lo[j] = acc;
    }
    float mx = fmaxf(lo[0], fmaxf(lo[1], lo[2]));
    float ex[3], se = 0.0f;
#pragma unroll
    for (int j = 0; j < 3; ++j) { ex[j] = __expf(lo[j] - mx); se += ex[j]; }
#pragma unroll
    for (int j = 0; j < 3; ++j) out[j] = ex[j] / se;
}

extern "C" void kernel_launch(void* const* d_in, const int* in_sizes, int n_in,
                              void* d_out, int out_size, void* d_ws, size_t ws_size,
                              hipStream_t stream) {
    const float* x    = (const float*)d_in[0];
    const float* W1   = (const float*)d_in[1];
    const float* as1w = (const float*)d_in[2];
    const float* ad1w = (const float*)d_in[3];
    const float* b1   = (const float*)d_in[4];
    const float* W2   = (const float*)d_in[5];
    const float* as2w = (const float*)d_in[6];
    const float* ad2w = (const float*)d_in[7];
    const float* b2w  = (const float*)d_in[8];
    const float* linW = (const float*)d_in[9];
    const float* linb = (const float*)d_in[10];
    const int*   ei   = (const int*)d_in[11];

    const int N  = in_sizes[0] / 64;       // 50000
    const int E  = in_sizes[11] / 2;       // 800000
    const int ET = E + N;

    float* ws = (float*)d_ws;
    // float region
    float* h1    = ws;                       // N*128 (hact after ELU)
    float* out1  = h1 + (size_t)N * 128;     // N*128 (written densely by pull_agg1)
    float* asrc1 = out1 + (size_t)N * 128;   // N*4
    float* adst1 = asrc1 + (size_t)N * 4;    // N*4
    float* asrc2 = adst1 + (size_t)N * 4;    // N
    float* adst2 = asrc2 + (size_t)N;        // N
    float* gsum  = adst2 + (size_t)N;        // 32
    // layer-2 aliases inside out1 (dead after elu_bias_k)
    float* h2    = out1;                     // N*32
    float* out2  = h2 + (size_t)N * 32;      // N*32
    // int region (16B-aligned: all previous sizes are multiples of 4 floats, gsum=32)
    int* deg     = (int*)(gsum + 32);        // N
    int* excl    = deg + N;                  // N
    int* cursor  = excl + N;                 // N
    int* row_ptr = cursor + N;               // N+8
    int* bsum    = row_ptr + N + 8;          // 256
    int* col     = bsum + 256;               // ET

    auto cdiv = [](int a, int b) { return (a + b - 1) / b; };
    const int NB256 = cdiv(N, 256);          // 196 scan blocks

    // ---- CSR build (shared by both layers) ----
    zero_i32<<<cdiv(N, 256), 256, 0, stream>>>(deg, N);
    hist_k<<<cdiv(ET, 256), 256, 0, stream>>>(ei, deg, E, N);
    scan1_k<<<NB256, 256, 0, stream>>>(deg, excl, bsum, N);
    scan2_k<<<1, 256, 0, stream>>>(bsum, NB256);
    scan3_k<<<cdiv(N + 1, 256), 256, 0, stream>>>(excl, bsum, row_ptr, cursor, N, ET);
    scatter_k<<<cdiv(ET, 256), 256, 0, stream>>>(ei, cursor, col, E, N);

    // ---- layer 1 ----
    gemm1_k<<<cdiv(N, 2), 256, 0, stream>>>(x, W1, h1, N);
    att_k<4><<<cdiv(N * 4, 256), 256, 0, stream>>>(h1, as1w, ad1w, asrc1, adst1, N);
    pull_agg1_k<<<cdiv(N, 4), 256, 0, stream>>>(row_ptr, col, asrc1, adst1, h1, out1, N);
    elu_bias_k<<<cdiv(N * 128, 256), 256, 0, stream>>>(out1, b1, h1, N * 128);  // hact -> h1

    // ---- layer 2 ----
    gemm2_k<<<cdiv(N, 8), 256, 0, stream>>>(h1, W2, h2, N);
    att_k<1><<<cdiv(N, 256), 256, 0, stream>>>(h2, as2w, ad2w, asrc2, adst2, N);
    pull_agg2_k<<<cdiv(N, 8), 256, 0, stream>>>(row_ptr, col, asrc2, adst2, h2, out2, N);

    // ---- readout ----
    fill_f32<<<1, 32, 0, stream>>>(gsum, 0.0f, 32);
    colmean_k<<<256, 256, 0, stream>>>(out2, gsum, N);
    final_k<<<1, 64, 0, stream>>>(gsum, b2w, linW, linb, (float*)d_out, N);
}

// Round 11
// 368.816 us; speedup vs baseline: 6.0088x; 1.2226x over previous
//
#include <hip/hip_runtime.h>
#include <math.h>

#define NEG_SLOPE 0.2f
#define G1B 1024   // persistent blocks, gemm1
#define G2B 1024   // persistent blocks, gemm2

static __device__ __forceinline__ void atomAdd(float* a, float v) {
    unsafeAtomicAdd(a, v);
}

// Edge-layout probe: int64 indices (<2^31) have all-zero odd 32-bit words.
static __device__ __forceinline__ bool edges_are_i64(const int* __restrict__ ei) {
    return (ei[1] | ei[3] | ei[5] | ei[7]) == 0;
}
static __device__ __forceinline__ int ldsrc(const int* __restrict__ ei, int e, int E, bool i64) {
    return i64 ? ei[2 * e] : ei[e];
}
static __device__ __forceinline__ int lddst(const int* __restrict__ ei, int e, int E, bool i64) {
    return i64 ? ei[2 * (E + e)] : ei[E + e];
}

__global__ void zero_i32(int* __restrict__ p, int n) {
    int i = blockIdx.x * blockDim.x + threadIdx.x;
    if (i < n) p[i] = 0;
}
__global__ void fill_f32(float* __restrict__ p, float v, int n) {
    int i = blockIdx.x * blockDim.x + threadIdx.x;
    if (i < n) p[i] = v;
}

// ---- CSR build (dst-sorted, self-loops included), shared by both layers ----
__global__ void hist_k(const int* __restrict__ ei, int* __restrict__ deg, int E, int N) {
    int e = blockIdx.x * blockDim.x + threadIdx.x;
    if (e >= E + N) return;
    bool i64 = edges_are_i64(ei);
    int d = (e < E) ? lddst(ei, e, E, i64) : (e - E);
    atomicAdd(&deg[d], 1);
}

__global__ __launch_bounds__(256) void scan1_k(const int* __restrict__ deg,
                                               int* __restrict__ excl,
                                               int* __restrict__ bsum, int N) {
    __shared__ int sd[256];
    int t = threadIdx.x, i = blockIdx.x * 256 + t;
    int v = (i < N) ? deg[i] : 0;
    sd[t] = v; __syncthreads();
    for (int off = 1; off < 256; off <<= 1) {
        int x = (t >= off) ? sd[t - off] : 0;
        __syncthreads();
        sd[t] += x;
        __syncthreads();
    }
    if (i < N) excl[i] = sd[t] - v;
    if (t == 255) bsum[blockIdx.x] = sd[255];
}
__global__ __launch_bounds__(256) void scan2_k(int* __restrict__ bsum, int nb) {
    __shared__ int sd[256];
    int t = threadIdx.x;
    int v = (t < nb) ? bsum[t] : 0;
    sd[t] = v; __syncthreads();
    for (int off = 1; off < 256; off <<= 1) {
        int x = (t >= off) ? sd[t - off] : 0;
        __syncthreads();
        sd[t] += x;
        __syncthreads();
    }
    if (t < nb) bsum[t] = sd[t] - v;
}
__global__ void scan3_k(const int* __restrict__ excl, const int* __restrict__ bsum,
                        int* __restrict__ row_ptr, int* __restrict__ cursor, int N, int ET) {
    int i = blockIdx.x * blockDim.x + threadIdx.x;
    if (i < N) { int r = excl[i] + bsum[i >> 8]; row_ptr[i] = r; cursor[i] = r; }
    if (i == N) row_ptr[N] = ET;
}
__global__ void scatter_k(const int* __restrict__ ei, int* __restrict__ cursor,
                          int* __restrict__ col, int E, int N) {
    int e = blockIdx.x * blockDim.x + threadIdx.x;
    if (e >= E + N) return;
    bool i64 = edges_are_i64(ei);
    int s, d;
    if (e < E) { s = ldsrc(ei, e, E, i64); d = lddst(ei, e, E, i64); }
    else       { s = d = e - E; }
    int pos = atomicAdd(&cursor[d], 1);
    col[pos] = s;
}

// ---- gemm1 (persistent blocks, W1 loaded once/block) + fused att logits ----
// h1[N,128] = x[N,64] @ W1[64,128]; asrc1/adst1[n,head] via width-32 shfl.
__global__ __launch_bounds__(256) void gemm1_k(const float* __restrict__ x,
                                               const float* __restrict__ W,
                                               const float* __restrict__ aws,
                                               const float* __restrict__ awd,
                                               float* __restrict__ h,
                                               float* __restrict__ as_,
                                               float* __restrict__ ad_, int N) {
    __shared__ float Ws[64 * 128];
    __shared__ float xs[128];
    int tid = threadIdx.x;
    for (int i = tid; i < 8192; i += 256) Ws[i] = W[i];
    const int pairs = (N + 1) / 2;
    for (int p = blockIdx.x; p < pairs; p += G1B) {
        __syncthreads();                       // also covers initial Ws fill
        if (tid < 128) {
            int r = 2 * p + tid / 64;
            xs[tid] = (r < N) ? x[(size_t)r * 64 + (tid & 63)] : 0.0f;
        }
        __syncthreads();
        int r = 2 * p + tid / 128;
        int j = tid & 127;
        if (r < N) {
            const float* xr = &xs[(tid / 128) * 64];
            float acc = 0.0f;
#pragma unroll
            for (int k = 0; k < 64; ++k) acc += xr[k] * Ws[k * 128 + j];
            h[(size_t)r * 128 + j] = acc;
            // fused attention logits: each 32-tid group = one head of one row
            float ps = acc * aws[j];
            float pd = acc * awd[j];
#pragma unroll
            for (int off = 16; off; off >>= 1) {
                ps += __shfl_down(ps, off, 32);
                pd += __shfl_down(pd, off, 32);
            }
            if ((tid & 31) == 0) {
                int head = j >> 5;
                as_[r * 4 + head] = ps;
                ad_[r * 4 + head] = pd;
            }
        }
    }
}

// ---- gemm2 (persistent) + fused att logits (H=1) ----
__global__ __launch_bounds__(256) void gemm2_k(const float* __restrict__ hact,
                                               const float* __restrict__ W,
                                               const float* __restrict__ aws,
                                               const float* __restrict__ awd,
                                               float* __restrict__ h2,
                                               float* __restrict__ as_,
                                               float* __restrict__ ad_, int N) {
    __shared__ float Ws[128 * 32];
    __shared__ float xs[8 * 128];
    int tid = threadIdx.x;
    for (int i = tid; i < 4096; i += 256) Ws[i] = W[i];
    const int groups = (N + 7) / 8;
    for (int g = blockIdx.x; g < groups; g += G2B) {
        __syncthreads();
        int r0 = g * 8;
        for (int i = tid; i < 1024; i += 256) {
            int r = r0 + i / 128;
            xs[i] = (r < N) ? hact[(size_t)r * 128 + (i & 127)] : 0.0f;
        }
        __syncthreads();
        int r = r0 + tid / 32, j = tid & 31;
        if (r < N) {
            const float* xr = &xs[(tid / 32) * 128];
            float acc = 0.0f;
#pragma unroll 16
            for (int k = 0; k < 128; ++k) acc += xr[k] * Ws[k * 32 + j];
            h2[(size_t)r * 32 + j] = acc;
            float ps = acc * aws[j];
            float pd = acc * awd[j];
#pragma unroll
            for (int off = 16; off; off >>= 1) {
                ps += __shfl_down(ps, off, 32);
                pd += __shfl_down(pd, off, 32);
            }
            if (j == 0) { as_[r] = ps; ad_[r] = pd; }
        }
    }
}

// ---- pull-mode aggregation, layer 1: unroll-4 gathers + fused bias/ELU ----
// One 64-lane wave per dst; lane owns channels 2l,2l+1 (head = l/16).
__global__ __launch_bounds__(256) void pull_agg1_k(const int* __restrict__ row_ptr,
                                                   const int* __restrict__ col,
                                                   const float* __restrict__ asrc,
                                                   const float* __restrict__ adst,
                                                   const float* __restrict__ h,
                                                   const float* __restrict__ b1,
                                                   float* __restrict__ hact, int N) {
    int wave = (blockIdx.x * 256 + threadIdx.x) >> 6;
    int lane = threadIdx.x & 63;
    if (wave >= N) return;
    const int d = wave;
    const int hd = lane >> 4;
    const float ad = adst[d * 4 + hd];
    const int beg = row_ptr[d], end = row_ptr[d + 1];
    float acc0 = 0.0f, acc1 = 0.0f, den = 0.0f;
    int i = beg;
    for (; i + 4 <= end; i += 4) {               // 4 gathers in flight
        int s0 = col[i], s1 = col[i + 1], s2 = col[i + 2], s3 = col[i + 3];
        float v0 = asrc[s0 * 4 + hd] + ad;
        float v1 = asrc[s1 * 4 + hd] + ad;
        float v2 = asrc[s2 * 4 + hd] + ad;
        float v3 = asrc[s3 * 4 + hd] + ad;
        const float2 g0 = *(const float2*)(h + (size_t)s0 * 128 + lane * 2);
        const float2 g1 = *(const float2*)(h + (size_t)s1 * 128 + lane * 2);
        const float2 g2 = *(const float2*)(h + (size_t)s2 * 128 + lane * 2);
        const float2 g3 = *(const float2*)(h + (size_t)s3 * 128 + lane * 2);
        v0 = v0 > 0.0f ? v0 : NEG_SLOPE * v0;  float p0 = __expf(v0);
        v1 = v1 > 0.0f ? v1 : NEG_SLOPE * v1;  float p1 = __expf(v1);
        v2 = v2 > 0.0f ? v2 : NEG_SLOPE * v2;  float p2 = __expf(v2);
        v3 = v3 > 0.0f ? v3 : NEG_SLOPE * v3;  float p3 = __expf(v3);
        den  += (p0 + p1) + (p2 + p3);
        acc0 += p0 * g0.x + p1 * g1.x + p2 * g2.x + p3 * g3.x;
        acc1 += p0 * g0.y + p1 * g1.y + p2 * g2.y + p3 * g3.y;
    }
    for (; i < end; ++i) {
        int s = col[i];
        float v = asrc[s * 4 + hd] + ad;
        v = v > 0.0f ? v : NEG_SLOPE * v;
        float p = __expf(v);
        const float2 g = *(const float2*)(h + (size_t)s * 128 + lane * 2);
        den += p; acc0 += p * g.x; acc1 += p * g.y;
    }
    float inv = 1.0f / den;                      // den>0: self-loop guaranteed
    float o0 = acc0 * inv + b1[lane * 2];
    float o1 = acc1 * inv + b1[lane * 2 + 1];
    o0 = o0 > 0.0f ? o0 : expm1f(o0);            // fused bias + ELU
    o1 = o1 > 0.0f ? o1 : expm1f(o1);
    *(float2*)(hact + (size_t)d * 128 + lane * 2) = make_float2(o0, o1);
}

// ---- pull-mode aggregation, layer 2 (H=1,C=32): 32-lane group per dst ----
__global__ __launch_bounds__(256) void pull_agg2_k(const int* __restrict__ row_ptr,
                                                   const int* __restrict__ col,
                                                   const float* __restrict__ asrc,
                                                   const float* __restrict__ adst,
                                                   const float* __restrict__ h,
                                                   float* __restrict__ out, int N) {
    int grp = (blockIdx.x * 256 + threadIdx.x) >> 5;
    int lane = threadIdx.x & 31;
    if (grp >= N) return;
    const int d = grp;
    const float ad = adst[d];
    const int beg = row_ptr[d], end = row_ptr[d + 1];
    float acc = 0.0f, den = 0.0f;
    int i = beg;
    for (; i + 4 <= end; i += 4) {
        int s0 = col[i], s1 = col[i + 1], s2 = col[i + 2], s3 = col[i + 3];
        float v0 = asrc[s0] + ad;
        float v1 = asrc[s1] + ad;
        float v2 = asrc[s2] + ad;
        float v3 = asrc[s3] + ad;
        float g0 = h[(size_t)s0 * 32 + lane];
        float g1 = h[(size_t)s1 * 32 + lane];
        float g2 = h[(size_t)s2 * 32 + lane];
        float g3 = h[(size_t)s3 * 32 + lane];
        v0 = v0 > 0.0f ? v0 : NEG_SLOPE * v0;  float p0 = __expf(v0);
        v1 = v1 > 0.0f ? v1 : NEG_SLOPE * v1;  float p1 = __expf(v1);
        v2 = v2 > 0.0f ? v2 : NEG_SLOPE * v2;  float p2 = __expf(v2);
        v3 = v3 > 0.0f ? v3 : NEG_SLOPE * v3;  float p3 = __expf(v3);
        den += (p0 + p1) + (p2 + p3);
        acc += p0 * g0 + p1 * g1 + p2 * g2 + p3 * g3;
    }
    for (; i < end; ++i) {
        int s = col[i];
        float v = asrc[s] + ad;
        v = v > 0.0f ? v : NEG_SLOPE * v;
        float p = __expf(v);
        den += p; acc += p * h[(size_t)s * 32 + lane];
    }
    out[(size_t)d * 32 + lane] = acc / den;
}

__global__ __launch_bounds__(256) void colmean_k(const float* __restrict__ out2,
                                                 float* __restrict__ gsum, int N) {
    __shared__ float lds[256];
    int tid = threadIdx.x;
    int c = tid % 32;
    int rg = tid / 32;
    float acc = 0.0f;
    for (int r = blockIdx.x * 8 + rg; r < N; r += gridDim.x * 8)
        acc += out2[(size_t)r * 32 + c];
    lds[tid] = acc;
    __syncthreads();
    if (tid < 32) {
        float s = 0.0f;
#pragma unroll
        for (int g = 0; g < 8; ++g) s += lds[g * 32 + tid];
        atomAdd(&gsum[tid], s);
    }
}

__global__ void final_k(const float* __restrict__ gsum, const float* __restrict__ b2w,
                        const float* __restrict__ linW, const float* __restrict__ linb,
                        float* __restrict__ out, int N) {
    if (threadIdx.x != 0 || blockIdx.x != 0) return;
    float g[32];
#pragma unroll
    for (int c = 0; c < 32; ++c) g[c] = gsum[c] / (float)N + b2w[c];
    float lo[3];
#pragma unroll
    for (int j = 0; j < 3; ++j) {
        float acc = linb[j];
#pragma unroll
        for (int c = 0; c < 32; ++c) acc += g[c] * linW[c * 3 + j];
        lo[j] = acc;
    }
    float mx = fmaxf(lo[0], fmaxf(lo[1], lo[2]));
    float ex[3], se = 0.0f;
#pragma unroll
    for (int j = 0; j < 3; ++j) { ex[j] = __expf(lo[j] - mx); se += ex[j]; }
#pragma unroll
    for (int j = 0; j < 3; ++j) out[j] = ex[j] / se;
}

extern "C" void kernel_launch(void* const* d_in, const int* in_sizes, int n_in,
                              void* d_out, int out_size, void* d_ws, size_t ws_size,
                              hipStream_t stream) {
    const float* x    = (const float*)d_in[0];
    const float* W1   = (const float*)d_in[1];
    const float* as1w = (const float*)d_in[2];
    const float* ad1w = (const float*)d_in[3];
    const float* b1   = (const float*)d_in[4];
    const float* W2   = (const float*)d_in[5];
    const float* as2w = (const float*)d_in[6];
    const float* ad2w = (const float*)d_in[7];
    const float* b2w  = (const float*)d_in[8];
    const float* linW = (const float*)d_in[9];
    const float* linb = (const float*)d_in[10];
    const int*   ei   = (const int*)d_in[11];

    const int N  = in_sizes[0] / 64;       // 50000
    const int E  = in_sizes[11] / 2;       // 800000
    const int ET = E + N;

    float* ws = (float*)d_ws;
    float* h1    = ws;                       // N*128: gemm1 out, pull_agg1 in
    float* hact  = h1 + (size_t)N * 128;     // N*128: pull_agg1 out (bias+ELU fused)
    float* asrc1 = hact + (size_t)N * 128;   // N*4
    float* adst1 = asrc1 + (size_t)N * 4;    // N*4
    float* asrc2 = adst1 + (size_t)N * 4;    // N
    float* adst2 = asrc2 + (size_t)N;        // N
    float* gsum  = adst2 + (size_t)N;        // 32
    // layer-2 aliases in the h1 region (dead after pull_agg1)
    float* h2    = h1;                       // N*32
    float* out2  = h1 + (size_t)N * 32;      // N*32
    // int region
    int* deg     = (int*)(gsum + 32);        // N
    int* excl    = deg + N;                  // N
    int* cursor  = excl + N;                 // N
    int* row_ptr = cursor + N;               // N+8
    int* bsum    = row_ptr + N + 8;          // 256
    int* col     = bsum + 256;               // ET

    auto cdiv = [](int a, int b) { return (a + b - 1) / b; };
    const int NB256 = cdiv(N, 256);

    // ---- CSR build (shared by both layers) ----
    zero_i32<<<cdiv(N, 256), 256, 0, stream>>>(deg, N);
    hist_k<<<cdiv(ET, 256), 256, 0, stream>>>(ei, deg, E, N);
    scan1_k<<<NB256, 256, 0, stream>>>(deg, excl, bsum, N);
    scan2_k<<<1, 256, 0, stream>>>(bsum, NB256);
    scan3_k<<<cdiv(N + 1, 256), 256, 0, stream>>>(excl, bsum, row_ptr, cursor, N, ET);
    scatter_k<<<cdiv(ET, 256), 256, 0, stream>>>(ei, cursor, col, E, N);

    // ---- layer 1 ----
    gemm1_k<<<G1B, 256, 0, stream>>>(x, W1, as1w, ad1w, h1, asrc1, adst1, N);
    pull_agg1_k<<<cdiv(N, 4), 256, 0, stream>>>(row_ptr, col, asrc1, adst1, h1, b1, hact, N);

    // ---- layer 2 ----
    gemm2_k<<<G2B, 256, 0, stream>>>(hact, W2, as2w, ad2w, h2, asrc2, adst2, N);
    pull_agg2_k<<<cdiv(N, 8), 256, 0, stream>>>(row_ptr, col, asrc2, adst2, h2, out2, N);

    // ---- readout ----
    fill_f32<<<1, 32, 0, stream>>>(gsum, 0.0f, 32);
    colmean_k<<<256, 256, 0, stream>>>(out2, gsum, N);
    final_k<<<1, 64, 0, stream>>>(gsum, b2w, linW, linb, (float*)d_out, N);
}

// Round 12
// 350.324 us; speedup vs baseline: 6.3259x; 1.0528x over previous
//
#include <hip/hip_runtime.h>
#include <hip/hip_fp16.h>
#include <math.h>

#define NEG_SLOPE 0.2f
#define G1B 1024   // persistent blocks, gemm1
#define G2B 1024   // persistent blocks, gemm2

static __device__ __forceinline__ void atomAdd(float* a, float v) {
    unsafeAtomicAdd(a, v);
}

// Edge-layout probe: int64 indices (<2^31) have all-zero odd 32-bit words.
static __device__ __forceinline__ bool edges_are_i64(const int* __restrict__ ei) {
    return (ei[1] | ei[3] | ei[5] | ei[7]) == 0;
}
static __device__ __forceinline__ int ldsrc(const int* __restrict__ ei, int e, int E, bool i64) {
    return i64 ? ei[2 * e] : ei[e];
}
static __device__ __forceinline__ int lddst(const int* __restrict__ ei, int e, int E, bool i64) {
    return i64 ? ei[2 * (E + e)] : ei[E + e];
}

// ---- CSR build (dst-sorted, self-loops included), shared by both layers ----
__global__ void hist_k(const int* __restrict__ ei, int* __restrict__ deg, int E, int N) {
    int e = blockIdx.x * blockDim.x + threadIdx.x;
    if (e >= E + N) return;
    bool i64 = edges_are_i64(ei);
    int d = (e < E) ? lddst(ei, e, E, i64) : (e - E);
    atomicAdd(&deg[d], 1);
}

__global__ __launch_bounds__(256) void scan1_k(const int* __restrict__ deg,
                                               int* __restrict__ excl,
                                               int* __restrict__ bsum, int N) {
    __shared__ int sd[256];
    int t = threadIdx.x, i = blockIdx.x * 256 + t;
    int v = (i < N) ? deg[i] : 0;
    sd[t] = v; __syncthreads();
    for (int off = 1; off < 256; off <<= 1) {
        int x = (t >= off) ? sd[t - off] : 0;
        __syncthreads();
        sd[t] += x;
        __syncthreads();
    }
    if (i < N) excl[i] = sd[t] - v;
    if (t == 255) bsum[blockIdx.x] = sd[255];
}
__global__ __launch_bounds__(256) void scan2_k(int* __restrict__ bsum, int nb) {
    __shared__ int sd[256];
    int t = threadIdx.x;
    int v = (t < nb) ? bsum[t] : 0;
    sd[t] = v; __syncthreads();
    for (int off = 1; off < 256; off <<= 1) {
        int x = (t >= off) ? sd[t - off] : 0;
        __syncthreads();
        sd[t] += x;
        __syncthreads();
    }
    if (t < nb) bsum[t] = sd[t] - v;
}
__global__ void scan3_k(const int* __restrict__ excl, const int* __restrict__ bsum,
                        int* __restrict__ row_ptr, int* __restrict__ cursor, int N, int ET) {
    int i = blockIdx.x * blockDim.x + threadIdx.x;
    if (i < N) { int r = excl[i] + bsum[i >> 8]; row_ptr[i] = r; cursor[i] = r; }
    if (i == N) row_ptr[N] = ET;
}
__global__ void scatter_k(const int* __restrict__ ei, int* __restrict__ cursor,
                          int* __restrict__ col, int E, int N) {
    int e = blockIdx.x * blockDim.x + threadIdx.x;
    if (e >= E + N) return;
    bool i64 = edges_are_i64(ei);
    int s, d;
    if (e < E) { s = ldsrc(ei, e, E, i64); d = lddst(ei, e, E, i64); }
    else       { s = d = e - E; }
    int pos = atomicAdd(&cursor[d], 1);
    col[pos] = s;
}

// ---- gemm1 (persistent, W1 once/block) + fused att logits; h1 stored fp16 ----
__global__ __launch_bounds__(256) void gemm1_k(const float* __restrict__ x,
                                               const float* __restrict__ W,
                                               const float* __restrict__ aws,
                                               const float* __restrict__ awd,
                                               __half* __restrict__ h,
                                               float* __restrict__ as_,
                                               float* __restrict__ ad_, int N) {
    __shared__ float Ws[64 * 128];
    __shared__ float xs[128];
    int tid = threadIdx.x;
    for (int i = tid; i < 8192; i += 256) Ws[i] = W[i];
    const int pairs = (N + 1) / 2;
    for (int p = blockIdx.x; p < pairs; p += G1B) {
        __syncthreads();                       // also covers initial Ws fill
        if (tid < 128) {
            int r = 2 * p + tid / 64;
            xs[tid] = (r < N) ? x[(size_t)r * 64 + (tid & 63)] : 0.0f;
        }
        __syncthreads();
        int r = 2 * p + tid / 128;
        int j = tid & 127;
        if (r < N) {
            const float* xr = &xs[(tid / 128) * 64];
            float acc = 0.0f;
#pragma unroll
            for (int k = 0; k < 64; ++k) acc += xr[k] * Ws[k * 128 + j];
            h[(size_t)r * 128 + j] = __float2half(acc);
            // fused attention logits (fp32 acc): 32-tid group = one head
            float ps = acc * aws[j];
            float pd = acc * awd[j];
#pragma unroll
            for (int off = 16; off; off >>= 1) {
                ps += __shfl_down(ps, off, 32);
                pd += __shfl_down(pd, off, 32);
            }
            if ((tid & 31) == 0) {
                int head = j >> 5;
                as_[r * 4 + head] = ps;
                ad_[r * 4 + head] = pd;
            }
        }
    }
}

// ---- gemm2 (persistent) + fused att logits (H=1); h2 stored fp16 ----
__global__ __launch_bounds__(256) void gemm2_k(const float* __restrict__ hact,
                                               const float* __restrict__ W,
                                               const float* __restrict__ aws,
                                               const float* __restrict__ awd,
                                               __half* __restrict__ h2,
                                               float* __restrict__ as_,
                                               float* __restrict__ ad_, int N) {
    __shared__ float Ws[128 * 32];
    __shared__ float xs[8 * 128];
    int tid = threadIdx.x;
    for (int i = tid; i < 4096; i += 256) Ws[i] = W[i];
    const int groups = (N + 7) / 8;
    for (int g = blockIdx.x; g < groups; g += G2B) {
        __syncthreads();
        int r0 = g * 8;
        for (int i = tid; i < 1024; i += 256) {
            int r = r0 + i / 128;
            xs[i] = (r < N) ? hact[(size_t)r * 128 + (i & 127)] : 0.0f;
        }
        __syncthreads();
        int r = r0 + tid / 32, j = tid & 31;
        if (r < N) {
            const float* xr = &xs[(tid / 32) * 128];
            float acc = 0.0f;
#pragma unroll 16
            for (int k = 0; k < 128; ++k) acc += xr[k] * Ws[k * 32 + j];
            h2[(size_t)r * 32 + j] = __float2half(acc);
            float ps = acc * aws[j];
            float pd = acc * awd[j];
#pragma unroll
            for (int off = 16; off; off >>= 1) {
                ps += __shfl_down(ps, off, 32);
                pd += __shfl_down(pd, off, 32);
            }
            if (j == 0) { as_[r] = ps; ad_[r] = pd; }
        }
    }
}

// ---- pull aggregation L1: unroll-8 fp16 gathers + fused bias/ELU ----
// One 64-lane wave per dst; lane owns channels 2l,2l+1 (head = l/16).
__global__ __launch_bounds__(256) void pull_agg1_k(const int* __restrict__ row_ptr,
                                                   const int* __restrict__ col,
                                                   const float* __restrict__ asrc,
                                                   const float* __restrict__ adst,
                                                   const __half* __restrict__ h,
                                                   const float* __restrict__ b1,
                                                   float* __restrict__ hact, int N) {
    int wave = (blockIdx.x * 256 + threadIdx.x) >> 6;
    int lane = threadIdx.x & 63;
    if (wave >= N) return;
    const int d = wave;
    const int hd = lane >> 4;
    const float ad = adst[d * 4 + hd];
    const int beg = row_ptr[d], end = row_ptr[d + 1];
    float acc0 = 0.0f, acc1 = 0.0f, den = 0.0f;
    int i = beg;
    for (; i + 8 <= end; i += 8) {               // 8 gathers in flight
        int s[8]; float v[8]; __half2 g[8];
#pragma unroll
        for (int u = 0; u < 8; ++u) s[u] = col[i + u];
#pragma unroll
        for (int u = 0; u < 8; ++u) v[u] = asrc[s[u] * 4 + hd] + ad;
#pragma unroll
        for (int u = 0; u < 8; ++u) g[u] = *(const __half2*)(h + (size_t)s[u] * 128 + lane * 2);
#pragma unroll
        for (int u = 0; u < 8; ++u) {
            float vv = v[u] > 0.0f ? v[u] : NEG_SLOPE * v[u];
            float p = __expf(vv);
            float2 gf = __half22float2(g[u]);
            den += p; acc0 += p * gf.x; acc1 += p * gf.y;
        }
    }
    for (; i < end; ++i) {
        int s = col[i];
        float v = asrc[s * 4 + hd] + ad;
        v = v > 0.0f ? v : NEG_SLOPE * v;
        float p = __expf(v);
        float2 gf = __half22float2(*(const __half2*)(h + (size_t)s * 128 + lane * 2));
        den += p; acc0 += p * gf.x; acc1 += p * gf.y;
    }
    float inv = 1.0f / den;                      // den>0: self-loop guaranteed
    float o0 = acc0 * inv + b1[lane * 2];
    float o1 = acc1 * inv + b1[lane * 2 + 1];
    o0 = o0 > 0.0f ? o0 : expm1f(o0);            // fused bias + ELU
    o1 = o1 > 0.0f ? o1 : expm1f(o1);
    *(float2*)(hact + (size_t)d * 128 + lane * 2) = make_float2(o0, o1);
}

// ---- pull aggregation L2 (H=1,C=32): 32-lane group per dst, fp16 gathers ----
__global__ __launch_bounds__(256) void pull_agg2_k(const int* __restrict__ row_ptr,
                                                   const int* __restrict__ col,
                                                   const float* __restrict__ asrc,
                                                   const float* __restrict__ adst,
                                                   const __half* __restrict__ h,
                                                   float* __restrict__ out, int N) {
    int grp = (blockIdx.x * 256 + threadIdx.x) >> 5;
    int lane = threadIdx.x & 31;
    if (grp >= N) return;
    const int d = grp;
    const float ad = adst[d];
    const int beg = row_ptr[d], end = row_ptr[d + 1];
    float acc = 0.0f, den = 0.0f;
    int i = beg;
    for (; i + 8 <= end; i += 8) {
        int s[8]; float v[8]; __half g[8];
#pragma unroll
        for (int u = 0; u < 8; ++u) s[u] = col[i + u];
#pragma unroll
        for (int u = 0; u < 8; ++u) v[u] = asrc[s[u]] + ad;
#pragma unroll
        for (int u = 0; u < 8; ++u) g[u] = h[(size_t)s[u] * 32 + lane];
#pragma unroll
        for (int u = 0; u < 8; ++u) {
            float vv = v[u] > 0.0f ? v[u] : NEG_SLOPE * v[u];
            float p = __expf(vv);
            den += p; acc += p * __half2float(g[u]);
        }
    }
    for (; i < end; ++i) {
        int s = col[i];
        float v = asrc[s] + ad;
        v = v > 0.0f ? v : NEG_SLOPE * v;
        float p = __expf(v);
        den += p; acc += p * __half2float(h[(size_t)s * 32 + lane]);
    }
    out[(size_t)d * 32 + lane] = acc / den;
}

__global__ __launch_bounds__(256) void colmean_k(const float* __restrict__ out2,
                                                 float* __restrict__ gsum, int N) {
    __shared__ float lds[256];
    int tid = threadIdx.x;
    int c = tid % 32;
    int rg = tid / 32;
    float acc = 0.0f;
    for (int r = blockIdx.x * 8 + rg; r < N; r += gridDim.x * 8)
        acc += out2[(size_t)r * 32 + c];
    lds[tid] = acc;
    __syncthreads();
    if (tid < 32) {
        float s = 0.0f;
#pragma unroll
        for (int g = 0; g < 8; ++g) s += lds[g * 32 + tid];
        atomAdd(&gsum[tid], s);
    }
}

__global__ void final_k(const float* __restrict__ gsum, const float* __restrict__ b2w,
                        const float* __restrict__ linW, const float* __restrict__ linb,
                        float* __restrict__ out, int N) {
    if (threadIdx.x != 0 || blockIdx.x != 0) return;
    float g[32];
#pragma unroll
    for (int c = 0; c < 32; ++c) g[c] = gsum[c] / (float)N + b2w[c];
    float lo[3];
#pragma unroll
    for (int j = 0; j < 3; ++j) {
        float acc = linb[j];
#pragma unroll
        for (int c = 0; c < 32; ++c) acc += g[c] * linW[c * 3 + j];
        lo[j] = acc;
    }
    float mx = fmaxf(lo[0], fmaxf(lo[1], lo[2]));
    float ex[3], se = 0.0f;
#pragma unroll
    for (int j = 0; j < 3; ++j) { ex[j] = __expf(lo[j] - mx); se += ex[j]; }
#pragma unroll
    for (int j = 0; j < 3; ++j) out[j] = ex[j] / se;
}

extern "C" void kernel_launch(void* const* d_in, const int* in_sizes, int n_in,
                              void* d_out, int out_size, void* d_ws, size_t ws_size,
                              hipStream_t stream) {
    const float* x    = (const float*)d_in[0];
    const float* W1   = (const float*)d_in[1];
    const float* as1w = (const float*)d_in[2];
    const float* ad1w = (const float*)d_in[3];
    const float* b1   = (const float*)d_in[4];
    const float* W2   = (const float*)d_in[5];
    const float* as2w = (const float*)d_in[6];
    const float* ad2w = (const float*)d_in[7];
    const float* b2w  = (const float*)d_in[8];
    const float* linW = (const float*)d_in[9];
    const float* linb = (const float*)d_in[10];
    const int*   ei   = (const int*)d_in[11];

    const int N  = in_sizes[0] / 64;       // 50000
    const int E  = in_sizes[11] / 2;       // 800000
    const int ET = E + N;

    float* ws = (float*)d_ws;
    // h1h region: N*128 halves = N*64 floats; later reused for h2h + out2
    __half* h1h  = (__half*)ws;                          // N*128 halves
    float*  hact = ws + (size_t)N * 64;                  // N*128 fp32
    float* asrc1 = hact + (size_t)N * 128;               // N*4
    float* adst1 = asrc1 + (size_t)N * 4;                // N*4
    float* asrc2 = adst1 + (size_t)N * 4;                // N
    float* adst2 = asrc2 + (size_t)N;                    // N
    float* gsum  = adst2 + (size_t)N;                    // 32
    // layer-2 aliases inside h1h region (dead after pull_agg1):
    __half* h2h  = (__half*)ws;                          // N*32 halves = N*16 fl
    float*  out2 = ws + (size_t)N * 16;                  // N*32 fp32 (fits: 16+32<=64)
    // int region
    int* deg     = (int*)(gsum + 32);        // N
    int* excl    = deg + N;                  // N
    int* cursor  = excl + N;                 // N
    int* row_ptr = cursor + N;               // N+8
    int* bsum    = row_ptr + N + 8;          // 256
    int* col     = bsum + 256;               // ET

    auto cdiv = [](int a, int b) { return (a + b - 1) / b; };
    const int NB256 = cdiv(N, 256);

    // zero deg + gsum via stream-ordered memsets (capture-legal)
    hipMemsetAsync(deg, 0, (size_t)N * sizeof(int), stream);
    hipMemsetAsync(gsum, 0, 32 * sizeof(float), stream);

    // ---- CSR build (shared by both layers) ----
    hist_k<<<cdiv(ET, 256), 256, 0, stream>>>(ei, deg, E, N);
    scan1_k<<<NB256, 256, 0, stream>>>(deg, excl, bsum, N);
    scan2_k<<<1, 256, 0, stream>>>(bsum, NB256);
    scan3_k<<<cdiv(N + 1, 256), 256, 0, stream>>>(excl, bsum, row_ptr, cursor, N, ET);
    scatter_k<<<cdiv(ET, 256), 256, 0, stream>>>(ei, cursor, col, E, N);

    // ---- layer 1 ----
    gemm1_k<<<G1B, 256, 0, stream>>>(x, W1, as1w, ad1w, h1h, asrc1, adst1, N);
    pull_agg1_k<<<cdiv(N, 4), 256, 0, stream>>>(row_ptr, col, asrc1, adst1, h1h, b1, hact, N);

    // ---- layer 2 ----
    gemm2_k<<<G2B, 256, 0, stream>>>(hact, W2, as2w, ad2w, h2h, asrc2, adst2, N);
    pull_agg2_k<<<cdiv(N, 8), 256, 0, stream>>>(row_ptr, col, asrc2, adst2, h2h, out2, N);

    // ---- readout ----
    colmean_k<<<256, 256, 0, stream>>>(out2, gsum, N);
    final_k<<<1, 64, 0, stream>>>(gsum, b2w, linW, linb, (float*)d_out, N);
}